// Round 22
// baseline (257.063 us; speedup 1.0000x reference)
//
#include <hip/hip_runtime.h>
#include <math.h>

// Problem constants (match reference)
#define NN 20000
#define EE 320000
#define DD 256
#define HH 8
#define DHD 32
#define EDF 64
#define FFD 1024

typedef unsigned short u16;
typedef __attribute__((ext_vector_type(8))) __bf16 bf16x8;
typedef __attribute__((ext_vector_type(8))) unsigned short u16x8;
typedef __attribute__((ext_vector_type(4))) float f32x4;

// workspace float offsets
#define XN_OFF   (0)
#define AGGB_OFF (2560000)
#define X1_OFF   (5120000)
#define QKV_OFF  (10240000)   // q bf16 [NN][256] + kv bf16 [NN][512] (k|v planes)
#define EP_OFF   (25600000)   // epc bf16 [EE][32] CSR-ordered
#define WT_OFF   (35840000)
#define BQKV_OFF (36240000)
#define CSR_OFF  (36250000)

__device__ __forceinline__ u16 f2bf(float f) {
    unsigned u = __float_as_uint(f);
    return (u16)((u + 0x7FFFu + ((u >> 16) & 1u)) >> 16);
}
__device__ __forceinline__ float bf2f(u16 h) {
    return __uint_as_float(((unsigned)h) << 16);
}
__device__ __forceinline__ float gelu_exact(float v) {
    return 0.5f * v * (1.0f + erff(v * 0.70710678118654752f));
}
// XCD-aware bijective swizzle (m204): XCD k gets contiguous work range.
__device__ __forceinline__ int xcd_swz(int bid, int nwg) {
    int q = nwg >> 3, r = nwg & 7;
    int xcd = bid & 7, i = bid >> 3;
    return (xcd < r ? xcd * (q + 1) : r * (q + 1) + (xcd - r) * q) + i;
}

#define GLDS16(g, l) __builtin_amdgcn_global_load_lds(             \
    (__attribute__((address_space(1))) void*)(g),                  \
    (__attribute__((address_space(3))) void*)(l), 16, 0, 0)

// -------- LayerNorm -> bf16 body --------
__device__ __forceinline__ void ln_body(const float* __restrict__ x,
                                        const float* __restrict__ g,
                                        const float* __restrict__ b,
                                        u16* __restrict__ out, int vb) {
    int row = vb * 4 + (threadIdx.x >> 6);
    if (row >= NN) return;
    int lane = threadIdx.x & 63;
    float4 v = *(const float4*)&x[(size_t)row * DD + lane * 4];
    float s  = v.x + v.y + v.z + v.w;
    float ss = v.x * v.x + v.y * v.y + v.z * v.z + v.w * v.w;
    #pragma unroll
    for (int o = 32; o >= 1; o >>= 1) {
        s  += __shfl_xor(s, o);
        ss += __shfl_xor(ss, o);
    }
    float mean = s * (1.0f / DD);
    float var  = ss * (1.0f / DD) - mean * mean;
    float inv  = rsqrtf(var + 1e-5f);
    float4 gg = *(const float4*)&g[lane * 4];
    float4 bb = *(const float4*)&b[lane * 4];
    ushort4 o4;
    o4.x = f2bf((v.x - mean) * inv * gg.x + bb.x);
    o4.y = f2bf((v.y - mean) * inv * gg.y + bb.y);
    o4.z = f2bf((v.z - mean) * inv * gg.z + bb.z);
    o4.w = f2bf((v.w - mean) * inv * gg.w + bb.w);
    *(ushort4*)&out[(size_t)row * DD + lane * 4] = o4;
}

// -------- 64x64 tile transpose+convert via LDS --------
__device__ __forceinline__ void transp_body(const float* __restrict__ src,
                                            u16* __restrict__ dst,
                                            int K, int N, int k0, int n0) {
    __shared__ float Ws[64][65];
    int t = threadIdx.x;
    int rr = t >> 4, cc = (t & 15) * 4;
    if (n0 + cc < N) {
        #pragma unroll
        for (int p = 0; p < 4; p++) {
            int k = rr + p * 16;
            float4 v = *(const float4*)&src[(size_t)(k0 + k) * N + n0 + cc];
            Ws[k][cc + 0] = v.x; Ws[k][cc + 1] = v.y;
            Ws[k][cc + 2] = v.z; Ws[k][cc + 3] = v.w;
        }
    }
    __syncthreads();
    int n = t >> 2, kc = (t & 3) * 16;
    if (n0 + n < N) {
        u16 o[16];
        #pragma unroll
        for (int j = 0; j < 16; j++) o[j] = f2bf(Ws[kc + j][n]);
        u16* dp = dst + (size_t)(n0 + n) * K + k0 + kc;
        *(ushort4*)(dp + 0)  = *(ushort4*)&o[0];
        *(ushort4*)(dp + 4)  = *(ushort4*)&o[4];
        *(ushort4*)(dp + 8)  = *(ushort4*)&o[8];
        *(ushort4*)(dp + 12) = *(ushort4*)&o[12];
    }
}

// ======== merged: weight transpose + bias + CSR count + LN1 ========
__global__ __launch_bounds__(256) void prep_count_ln_kernel(
    const float* __restrict__ Wq, const float* __restrict__ Wk,
    const float* __restrict__ Wv, const float* __restrict__ Wo,
    const float* __restrict__ W1, const float* __restrict__ W2,
    const float* __restrict__ We,
    const float* __restrict__ bq, const float* __restrict__ bk,
    const float* __restrict__ bv,
    u16* __restrict__ WqkvT, u16* __restrict__ WoT, u16* __restrict__ W1T,
    u16* __restrict__ W2T, u16* __restrict__ WeT, float* __restrict__ bqkv,
    const int* __restrict__ ei, int* __restrict__ counts,
    const float* __restrict__ x, const float* __restrict__ ln1g,
    const float* __restrict__ ln1b, u16* __restrict__ xn) {
    int b = blockIdx.x;
    if (b < 193) {
        const float* src; u16* dst; int K, N, ti;
        if      (b < 16)  { src = Wq; dst = WqkvT;          K = 256;  N = 256;  ti = b; }
        else if (b < 32)  { src = Wk; dst = WqkvT + 65536;  K = 256;  N = 256;  ti = b - 16; }
        else if (b < 48)  { src = Wv; dst = WqkvT + 131072; K = 256;  N = 256;  ti = b - 32; }
        else if (b < 64)  { src = Wo; dst = WoT;            K = 256;  N = 256;  ti = b - 48; }
        else if (b < 128) { src = W1; dst = W1T;            K = 256;  N = 1024; ti = b - 64; }
        else if (b < 192) { src = W2; dst = W2T;            K = 1024; N = 256;  ti = b - 128; }
        else              { src = We; dst = WeT;            K = 64;   N = 32;   ti = 0; }
        int ntn = N >> 6; if (ntn == 0) ntn = 1;
        int tk = ti / ntn, tn = ti % ntn;
        transp_body(src, dst, K, N, tk * 64, tn * 64);
    } else if (b == 193) {
        int t = threadIdx.x;
        bqkv[t] = bq[t];
        bqkv[256 + t] = bk[t];
        bqkv[512 + t] = bv[t];
    } else if (b < 1444) {
        int e = (b - 194) * 256 + threadIdx.x;
        if (e < EE) atomicAdd(&counts[ei[EE + e]], 1);
    } else {
        ln_body(x, ln1g, ln1b, xn, b - 1444);
    }
}

// ======== bf16 MFMA GEMM body ========
// EPI: 0 fp32 out | 1 gelu->bf16 | 2 fp32 res+scale*(acc+bias)
//      3 QKV split (q bf16 scaled, kv k|v planes)
//      4 Wo+LN2 FUSED: x1 = res + scale*(acc+bias) (fp32 out) AND
//        xn = LN(x1)*lng+lnb (bf16 out). Requires BN == N (block owns
//        full rows); per-row stats via shfl + LDS combine of wc halves.
template <int BM, int BN, int EPI>
__device__ __forceinline__ void gemm_body(
    char* smem,
    const u16* __restrict__ A, const u16* __restrict__ BT,
    const float* __restrict__ bias,
    float* __restrict__ Cf, u16* __restrict__ Cb,
    const float* __restrict__ res, const float* __restrict__ scale,
    int M, int K, int N, int bxx, int byy,
    const float* __restrict__ lng = nullptr,
    const float* __restrict__ lnb = nullptr,
    u16* __restrict__ xnout = nullptr)
{
    constexpr int FM = BM / 32, FN = BN / 32;
    constexpr int nA = BM / 32, nB = BN / 32;
    constexpr int NST = (nA > nB) ? nA : nB;
    u16* Asm = (u16*)smem;
    u16* Bsm = (u16*)(smem + BM * 64 * 2);
    const int tid  = threadIdx.x;
    const int lane = tid & 63;
    const int w    = tid >> 6;
    const int wr   = w >> 1, wc = w & 1;
    const int bm   = bxx * BM;
    const int bn   = byy * BN;

    f32x4 acc[FM][FN] = {};

    int st_row[NST], st_src[NST], st_dst[NST];
    #pragma unroll
    for (int i = 0; i < NST; i++) {
        int base  = i * 4096 + w * 1024;
        int off   = base + lane * 16;
        int row   = off >> 7;
        int inner = off & 127;
        st_row[i] = row;
        st_src[i] = (inner ^ ((row & 7) << 4)) >> 1;
        st_dst[i] = base;
    }
    const int arow0 = wr * (BM / 2) + (lane & 15);
    const int brow0 = wc * (BN / 2) + (lane & 15);
    const int kb0   = (lane >> 4) * 16;

    for (int k0 = 0; k0 < K; k0 += 64) {
        #pragma unroll
        for (int i = 0; i < nA; i++) {
            int r = bm + st_row[i]; if (r > M - 1) r = M - 1;
            GLDS16(A + (size_t)r * K + k0 + st_src[i], (char*)Asm + st_dst[i]);
        }
        #pragma unroll
        for (int i = 0; i < nB; i++) {
            int r = bn + st_row[i];
            GLDS16(BT + (size_t)r * K + k0 + st_src[i], (char*)Bsm + st_dst[i]);
        }
        asm volatile("s_waitcnt vmcnt(0)" ::: "memory");
        __syncthreads();
        #pragma unroll
        for (int s = 0; s < 2; s++) {
            bf16x8 af[FM], bfv[FN];
            #pragma unroll
            for (int i = 0; i < FM; i++) {
                int row  = arow0 + i * 16;
                int byte = (row << 7) + ((kb0 + s * 64) ^ ((row & 7) << 4));
                af[i] = *(const bf16x8*)((const char*)Asm + byte);
            }
            #pragma unroll
            for (int j = 0; j < FN; j++) {
                int row  = brow0 + j * 16;
                int byte = (row << 7) + ((kb0 + s * 64) ^ ((row & 7) << 4));
                bfv[j] = *(const bf16x8*)((const char*)Bsm + byte);
            }
            #pragma unroll
            for (int i = 0; i < FM; i++)
                #pragma unroll
                for (int j = 0; j < FN; j++)
                    acc[i][j] = __builtin_amdgcn_mfma_f32_16x16x32_bf16(
                        af[i], bfv[j], acc[i][j], 0, 0, 0);
        }
        __syncthreads();
    }

    const int col0 = bn + wc * (BN / 2) + (lane & 15);
    const int row0 = bm + wr * (BM / 2) + ((lane >> 4) << 2);

    if constexpr (EPI == 4) {
        float sc = scale[0];
        float rs[FM][4], rss[FM][4];
        #pragma unroll
        for (int i = 0; i < FM; i++)
            #pragma unroll
            for (int r = 0; r < 4; r++) { rs[i][r] = 0.f; rss[i][r] = 0.f; }
        // transform to x1, write fp32, gather per-row partial stats
        #pragma unroll
        for (int i = 0; i < FM; i++) {
            #pragma unroll
            for (int j = 0; j < FN; j++) {
                int col = col0 + j * 16;
                float bb = bias[col];
                #pragma unroll
                for (int r = 0; r < 4; r++) {
                    int row = row0 + i * 16 + r;
                    float o = res[(size_t)row * N + col] + sc * (acc[i][j][r] + bb);
                    acc[i][j][r] = o;
                    if (row < M) Cf[(size_t)row * N + col] = o;
                    rs[i][r] += o;
                    rss[i][r] += o * o;
                }
            }
        }
        // reduce across the 16 lanes sharing each row
        #pragma unroll
        for (int i = 0; i < FM; i++)
            #pragma unroll
            for (int r = 0; r < 4; r++) {
                #pragma unroll
                for (int o = 8; o >= 1; o >>= 1) {
                    rs[i][r]  += __shfl_xor(rs[i][r], o);
                    rss[i][r] += __shfl_xor(rss[i][r], o);
                }
            }
        // combine wc halves via LDS (smem free after final k-loop barrier)
        float* lnbuf = (float*)smem;   // [64 rows][2 wc][2 {s,ss}]
        if ((lane & 15) == 0) {
            #pragma unroll
            for (int i = 0; i < FM; i++)
                #pragma unroll
                for (int r = 0; r < 4; r++) {
                    int lrow = wr * (BM / 2) + ((lane >> 4) << 2) + i * 16 + r;
                    lnbuf[(lrow * 2 + wc) * 2 + 0] = rs[i][r];
                    lnbuf[(lrow * 2 + wc) * 2 + 1] = rss[i][r];
                }
        }
        __syncthreads();
        #pragma unroll
        for (int i = 0; i < FM; i++) {
            #pragma unroll
            for (int r = 0; r < 4; r++) {
                int lrow = wr * (BM / 2) + ((lane >> 4) << 2) + i * 16 + r;
                float s2  = lnbuf[(lrow * 2 + 0) * 2 + 0] + lnbuf[(lrow * 2 + 1) * 2 + 0];
                float ss2 = lnbuf[(lrow * 2 + 0) * 2 + 1] + lnbuf[(lrow * 2 + 1) * 2 + 1];
                float mean = s2 * (1.0f / DD);
                float var  = ss2 * (1.0f / DD) - mean * mean;
                float inv  = rsqrtf(var + 1e-5f);
                int row = row0 + i * 16 + r;
                if (row < M) {
                    #pragma unroll
                    for (int j = 0; j < FN; j++) {
                        int col = col0 + j * 16;
                        xnout[(size_t)row * N + col] =
                            f2bf((acc[i][j][r] - mean) * inv * lng[col] + lnb[col]);
                    }
                }
            }
        }
    } else {
        float sc = 0.f;
        if constexpr (EPI == 2) sc = scale[0];
        #pragma unroll
        for (int i = 0; i < FM; i++) {
            #pragma unroll
            for (int j = 0; j < FN; j++) {
                int col = col0 + j * 16;
                float bb = bias[col];
                #pragma unroll
                for (int r = 0; r < 4; r++) {
                    int row = row0 + i * 16 + r;
                    if (row < M) {
                        float o = acc[i][j][r] + bb;
                        if constexpr (EPI == 1) {
                            Cb[(size_t)row * N + col] = f2bf(gelu_exact(o));
                        } else if constexpr (EPI == 2) {
                            Cf[(size_t)row * N + col] = res[(size_t)row * N + col] + sc * o;
                        } else if constexpr (EPI == 3) {
                            if (col < 256) {
                                Cb[(size_t)row * 256 + col] = f2bf(o * 0.17677669529663689f);
                            } else if (col < 512) {
                                Cb[(size_t)NN * 256 + (size_t)row * 512 + (col - 256)] = f2bf(o);
                            } else {
                                Cb[(size_t)NN * 256 + (size_t)row * 512 + 256 + (col - 512)] = f2bf(o);
                            }
                        } else {
                            Cf[(size_t)row * N + col] = o;
                        }
                    }
                }
            }
        }
    }
}

// 1D-launched GEMM with XCD swizzle (col-tile fastest within an XCD range)
template <int BM, int BN, int EPI>
__global__ __launch_bounds__(256) void gemm_bf16(
    const u16* __restrict__ A, const u16* __restrict__ BT,
    const float* __restrict__ bias,
    float* __restrict__ Cf, u16* __restrict__ Cb,
    const float* __restrict__ res, const float* __restrict__ scale,
    int M, int K, int N, int nwg, int nby,
    const float* lng = nullptr, const float* lnb = nullptr,
    u16* xnout = nullptr) {
    __shared__ char smem[(BM + BN) * 64 * 2];
    int wk = xcd_swz(blockIdx.x, nwg);
    gemm_body<BM, BN, EPI>(smem, A, BT, bias, Cf, Cb, res, scale, M, K, N,
                           wk / nby, wk % nby, lng, lnb, xnout);
}

// -------- edge projection body (128 edges/block) --------
__device__ __forceinline__ void ep_body(char* smem,
                                        const float* __restrict__ ef,
                                        const u16* __restrict__ WeT,
                                        const float* __restrict__ be,
                                        const int* __restrict__ epos,
                                        u16* __restrict__ epc, int blk) {
    const int tid  = threadIdx.x;
    const int lane = tid & 63;
    const int w    = tid >> 6;
    const int e0b  = blk * 128;

    #pragma unroll
    for (int j = 0; j < 8; j++) {
        int gidx = (w * 8 + j) * 64 + lane;
        int e    = gidx >> 4;
        int cs   = (gidx & 15) << 4;
        int c    = cs ^ ((e & 15) << 4);
        GLDS16((const char*)ef + (size_t)(e0b + e) * 256 + c,
               smem + (w * 8 + j) * 1024);
    }
    asm volatile("s_waitcnt vmcnt(0)" ::: "memory");
    __syncthreads();

    const int ar = lane & 15;
    f32x4 acc[2][2] = {};
    #pragma unroll
    for (int t = 0; t < 2; t++) {
        int r = w * 32 + t * 16 + ar;
        const char* base = smem + r * 256;
        #pragma unroll
        for (int s = 0; s < 2; s++) {
            int cbyte = (lane >> 4) * 32 + s * 128;
            float4 a0 = *(const float4*)(base + ((cbyte)      ^ (ar << 4)));
            float4 a1 = *(const float4*)(base + ((cbyte + 16) ^ (ar << 4)));
            bf16x8 af;
            af[0] = (__bf16)a0.x; af[1] = (__bf16)a0.y; af[2] = (__bf16)a0.z; af[3] = (__bf16)a0.w;
            af[4] = (__bf16)a1.x; af[5] = (__bf16)a1.y; af[6] = (__bf16)a1.z; af[7] = (__bf16)a1.w;
            #pragma unroll
            for (int j = 0; j < 2; j++) {
                bf16x8 bf = *(const bf16x8*)&WeT[(size_t)(j * 16 + ar) * EDF + s * 32 + ((lane >> 4) * 8)];
                acc[t][j] = __builtin_amdgcn_mfma_f32_16x16x32_bf16(af, bf, acc[t][j], 0, 0, 0);
            }
        }
    }
    __syncthreads();
    u16* outl = (u16*)smem;
    int* posl = (int*)(smem + 8192);
    if (tid < 128) posl[tid] = epos[e0b + tid];
    const int row0 = (lane >> 4) << 2;
    #pragma unroll
    for (int t = 0; t < 2; t++)
        #pragma unroll
        for (int j = 0; j < 2; j++)
            #pragma unroll
            for (int rr = 0; rr < 4; rr++) {
                int row = w * 32 + t * 16 + row0 + rr;
                int col = j * 16 + ar;
                outl[row * 32 + col] = f2bf(acc[t][j][rr] + be[col]);
            }
    __syncthreads();
    #pragma unroll
    for (int c2 = 0; c2 < 2; c2++) {
        int ch = tid + c2 * 256;
        int row = ch >> 2, part = ch & 3;
        u16x8 v = *(const u16x8*)&outl[row * 32 + part * 8];
        *(u16x8*)&epc[(size_t)posl[row] * DHD + part * 8] = v;
    }
}

// ======== merged: QKV GEMM (942, XCD-swizzled) + edge projection (2500) ========
__global__ __launch_bounds__(256) void qkv_ep_kernel(
    const u16* __restrict__ xn, const u16* __restrict__ WqkvT,
    const float* __restrict__ bqkv, u16* __restrict__ qb,
    const float* __restrict__ ef, const u16* __restrict__ WeT,
    const float* __restrict__ be, const int* __restrict__ epos,
    u16* __restrict__ epc) {
    __shared__ char smem[32768];
    int b = blockIdx.x;
    if (b < 942) {
        int wk = xcd_swz(b, 942);
        gemm_body<128, 128, 3>(smem, xn, WqkvT, bqkv, nullptr, qb, nullptr,
                               nullptr, NN, DD, 768, wk / 6, wk % 6);
    } else {
        ep_body(smem, ef, WeT, be, epos, epc, b - 942);
    }
}

// ======== CSR scan + degree histogram ========
__global__ __launch_bounds__(1024) void scan_kernel(const int* __restrict__ counts,
                                                    int* __restrict__ row_start,
                                                    int* __restrict__ cursor,
                                                    int* __restrict__ dcursor) {
    __shared__ int part[1024];
    __shared__ int hist[64][16];
    const int CH = 20;
    int t = threadIdx.x;
    if (t < 64) {
        #pragma unroll
        for (int s = 0; s < 16; s++) hist[t][s] = 0;
    }
    __syncthreads();
    int base = t * CH;
    int sub = t & 15;
    int loc[CH];
    int s = 0;
    #pragma unroll
    for (int i = 0; i < CH; i++) {
        int idx = base + i;
        int c = (idx < NN) ? counts[idx] : 0;
        if (idx < NN) atomicAdd(&hist[min(c, 63)][sub], 1);
        loc[i] = s;
        s += c;
    }
    part[t] = s;
    __syncthreads();
    for (int o = 1; o < 1024; o <<= 1) {
        int vv = (t >= o) ? part[t - o] : 0;
        __syncthreads();
        part[t] += vv;
        __syncthreads();
    }
    int off = (t > 0) ? part[t - 1] : 0;
    #pragma unroll
    for (int i = 0; i < CH; i++) {
        int idx = base + i;
        if (idx < NN) {
            int rs = off + loc[i];
            row_start[idx] = rs;
            cursor[idx] = rs;
        }
    }
    if (t == 1023) row_start[NN] = part[1023];
    if (t < 64) {
        int st = 0;
        for (int b = 63; b > t; --b) {
            #pragma unroll
            for (int sj = 0; sj < 16; sj++) st += hist[b][sj];
        }
        dcursor[t] = st;
    }
}

// fill CSR + epos + block-aggregated counting sort
__global__ __launch_bounds__(256) void fill_kernel(const int* __restrict__ ei,
                                                   const float* __restrict__ ew,
                                                   int* __restrict__ cursor,
                                                   int2* __restrict__ csr,
                                                   int* __restrict__ epos,
                                                   const int* __restrict__ counts,
                                                   int* __restrict__ dcursor,
                                                   int* __restrict__ order) {
    int b = blockIdx.x;
    if (b < EE / 256) {
        int e = b * 256 + threadIdx.x;
        int src = ei[e];
        int dst = ei[EE + e];
        int pos = atomicAdd(&cursor[dst], 1);
        csr[pos] = make_int2(src, __float_as_int(ew[e] * 1.44269504088896f));
        epos[e] = pos;
    } else {
        __shared__ int lhist[64];
        __shared__ int lbase[64];
        int t = threadIdx.x;
        if (t < 64) lhist[t] = 0;
        __syncthreads();
        int n = (b - EE / 256) * 256 + t;
        int d = -1, lpos = 0;
        if (n < NN) {
            d = min(counts[n], 63);
            lpos = atomicAdd(&lhist[d], 1);
        }
        __syncthreads();
        if (t < 64 && lhist[t] > 0) lbase[t] = atomicAdd(&dcursor[t], lhist[t]);
        __syncthreads();
        if (n < NN) order[lbase[d] + lpos] = n;
    }
}

// ======== fused gather attention: ONE WAVE per dst node, degree-sorted ========
__global__ __launch_bounds__(256) void attn_kernel(const u16* __restrict__ qb,
                                                   const u16* __restrict__ kv,
                                                   const u16* __restrict__ epc,
                                                   const int2* __restrict__ csr,
                                                   const int* __restrict__ row_start,
                                                   const int* __restrict__ order,
                                                   u16* __restrict__ aggb) {
    const int dst  = order[blockIdx.x * 4 + (threadIdx.x >> 6)];
    const int lane = threadIdx.x & 63;
    const int g    = lane & 7;
    const int d0   = (lane >> 3) * 32 + g * 4;
    const int beg = row_start[dst];
    const int end = row_start[dst + 1];
    ushort4 q4 = *(const ushort4*)&qb[(size_t)dst * DD + d0];
    float4 qv = make_float4(bf2f(q4.x), bf2f(q4.y), bf2f(q4.z), bf2f(q4.w));
    float ss = 0.f;
    float4 acc = make_float4(0.f, 0.f, 0.f, 0.f);

    int i = beg;
    if ((i & 1) && i < end) {
        int2 p = csr[i];
        ushort4 ka = *(const ushort4*)&kv[(size_t)p.x * 512 + d0];
        ushort4 va = *(const ushort4*)&kv[(size_t)p.x * 512 + 256 + d0];
        ushort4 e4 = *(const ushort4*)&epc[(size_t)i * DHD + g * 4];
        float k0 = bf2f(ka.x) + bf2f(e4.x);
        float k1 = bf2f(ka.y) + bf2f(e4.y);
        float k2 = bf2f(ka.z) + bf2f(e4.z);
        float k3 = bf2f(ka.w) + bf2f(e4.w);
        float pv = fmaf(qv.x, k0, fmaf(qv.y, k1, fmaf(qv.z, k2, qv.w * k3)));
        #pragma unroll
        for (int o = 4; o >= 1; o >>= 1) pv += __shfl_xor(pv, o);
        float wq = exp2f(pv * __int_as_float(p.y));
        ss += wq;
        acc.x = fmaf(wq, bf2f(va.x), acc.x);
        acc.y = fmaf(wq, bf2f(va.y), acc.y);
        acc.z = fmaf(wq, bf2f(va.z), acc.z);
        acc.w = fmaf(wq, bf2f(va.w), acc.w);
        ++i;
    }
    for (; i + 4 <= end; i += 4) {
        int4 c01 = *(const int4*)&csr[i];
        int4 c23 = *(const int4*)&csr[i + 2];
        int   sr[4] = {c01.x, c01.z, c23.x, c23.z};
        float wt[4] = {__int_as_float(c01.y), __int_as_float(c01.w),
                       __int_as_float(c23.y), __int_as_float(c23.w)};
        ushort4 ka[4], va[4], e4[4];
        #pragma unroll
        for (int u = 0; u < 4; u++) {
            ka[u] = *(const ushort4*)&kv[(size_t)sr[u] * 512 + d0];
            va[u] = *(const ushort4*)&kv[(size_t)sr[u] * 512 + 256 + d0];
            e4[u] = *(const ushort4*)&epc[(size_t)(i + u) * DHD + g * 4];
        }
        float pp[4];
        #pragma unroll
        for (int u = 0; u < 4; u++) {
            float k0 = bf2f(ka[u].x) + bf2f(e4[u].x);
            float k1 = bf2f(ka[u].y) + bf2f(e4[u].y);
            float k2 = bf2f(ka[u].z) + bf2f(e4[u].z);
            float k3 = bf2f(ka[u].w) + bf2f(e4[u].w);
            pp[u] = fmaf(qv.x, k0, fmaf(qv.y, k1, fmaf(qv.z, k2, qv.w * k3)));
        }
        #pragma unroll
        for (int o = 4; o >= 1; o >>= 1) {
            #pragma unroll
            for (int u = 0; u < 4; u++) pp[u] += __shfl_xor(pp[u], o);
        }
        #pragma unroll
        for (int u = 0; u < 4; u++) {
            float wq = exp2f(pp[u] * wt[u]);
            ss += wq;
            acc.x = fmaf(wq, bf2f(va[u].x), acc.x);
            acc.y = fmaf(wq, bf2f(va[u].y), acc.y);
            acc.z = fmaf(wq, bf2f(va[u].z), acc.z);
            acc.w = fmaf(wq, bf2f(va[u].w), acc.w);
        }
    }
    for (; i < end; ++i) {
        int2 p = csr[i];
        ushort4 ka = *(const ushort4*)&kv[(size_t)p.x * 512 + d0];
        ushort4 va = *(const ushort4*)&kv[(size_t)p.x * 512 + 256 + d0];
        ushort4 e4 = *(const ushort4*)&epc[(size_t)i * DHD + g * 4];
        float k0 = bf2f(ka.x) + bf2f(e4.x);
        float k1 = bf2f(ka.y) + bf2f(e4.y);
        float k2 = bf2f(ka.z) + bf2f(e4.z);
        float k3 = bf2f(ka.w) + bf2f(e4.w);
        float pv = fmaf(qv.x, k0, fmaf(qv.y, k1, fmaf(qv.z, k2, qv.w * k3)));
        #pragma unroll
        for (int o = 4; o >= 1; o >>= 1) pv += __shfl_xor(pv, o);
        float wq = exp2f(pv * __int_as_float(p.y));
        ss += wq;
        acc.x = fmaf(wq, bf2f(va.x), acc.x);
        acc.y = fmaf(wq, bf2f(va.y), acc.y);
        acc.z = fmaf(wq, bf2f(va.z), acc.z);
        acc.w = fmaf(wq, bf2f(va.w), acc.w);
    }
    float inv = (end > beg) ? 1.f / ss : 0.f;
    ushort4 o4;
    o4.x = f2bf(acc.x * inv);
    o4.y = f2bf(acc.y * inv);
    o4.z = f2bf(acc.z * inv);
    o4.w = f2bf(acc.w * inv);
    *(ushort4*)&aggb[(size_t)dst * DD + d0] = o4;
}

extern "C" void kernel_launch(void* const* d_in, const int* in_sizes, int n_in,
                              void* d_out, int out_size, void* d_ws, size_t ws_size,
                              hipStream_t stream) {
    const float* x    = (const float*)d_in[0];
    const float* ef   = (const float*)d_in[1];
    const float* ew   = (const float*)d_in[2];
    const int*   ei   = (const int*)d_in[3];
    const float* Wq   = (const float*)d_in[4];
    const float* bq   = (const float*)d_in[5];
    const float* Wk   = (const float*)d_in[6];
    const float* bk   = (const float*)d_in[7];
    const float* Wv   = (const float*)d_in[8];
    const float* bv   = (const float*)d_in[9];
    const float* We   = (const float*)d_in[10];
    const float* be   = (const float*)d_in[11];
    const float* Wo   = (const float*)d_in[12];
    const float* bo   = (const float*)d_in[13];
    const float* ln1g = (const float*)d_in[14];
    const float* ln1b = (const float*)d_in[15];
    const float* ln2g = (const float*)d_in[16];
    const float* ln2b = (const float*)d_in[17];
    const float* W1   = (const float*)d_in[18];
    const float* b1   = (const float*)d_in[19];
    const float* W2   = (const float*)d_in[20];
    const float* b2   = (const float*)d_in[21];
    const float* alpha = (const float*)d_in[22];
    const float* beta  = (const float*)d_in[23];

    float* ws    = (float*)d_ws;
    u16*   xn    = (u16*)(ws + XN_OFF);
    u16*   aggb  = (u16*)(ws + AGGB_OFF);
    float* x1    = ws + X1_OFF;
    u16*   qb    = (u16*)(ws + QKV_OFF);
    u16*   kv    = qb + (size_t)NN * 256;
    u16*   ff1   = (u16*)(ws + QKV_OFF);
    u16*   epc   = (u16*)(ws + EP_OFF);
    u16*   wt    = (u16*)(ws + WT_OFF);
    u16*   WqkvT = wt;
    u16*   WoT   = wt + 768 * 256;
    u16*   W1T   = WoT + 256 * 256;
    u16*   W2T   = W1T + 1024 * 256;
    u16*   WeT   = W2T + 256 * 1024;
    float* bqkv  = ws + BQKV_OFF;
    float* out   = (float*)d_out;

    int*  counts    = (int*)(ws + CSR_OFF);
    int*  row_start = counts + NN;
    int*  cursor    = row_start + NN + 1;
    int2* csr       = (int2*)(counts + 60004);
    int*  epos      = counts + 60004 + 2 * EE;
    int*  order     = epos + EE;
    int*  dcursor   = order + NN;

    hipMemsetAsync(counts, 0, (size_t)NN * sizeof(int), stream);

    prep_count_ln_kernel<<<6444, 256, 0, stream>>>(
        Wq, Wk, Wv, Wo, W1, W2, We, bq, bk, bv,
        WqkvT, WoT, W1T, W2T, WeT, bqkv, ei, counts, x, ln1g, ln1b, xn);

    scan_kernel<<<1, 1024, 0, stream>>>(counts, row_start, cursor, dcursor);
    fill_kernel<<<EE / 256 + (NN + 255) / 256, 256, 0, stream>>>(
        ei, ew, cursor, csr, epos, counts, dcursor, order);

    // merged QKV GEMM (942, XCD-swizzled) + edge projection (2500)
    qkv_ep_kernel<<<3442, 256, 0, stream>>>(xn, WqkvT, bqkv, qb,
                                            ef, WeT, be, epos, epc);

    attn_kernel<<<NN / 4, 256, 0, stream>>>(qb, kv, epc, csr, row_start, order, aggb);

    // FUSED Wo GEMM + residual + LN2: x1 fp32 AND xn bf16 in one pass
    // (64x256 tile: block owns full rows; 313 blocks, nby=1)
    gemm_bf16<64, 256, 4><<<313, 256, 0, stream>>>(
        aggb, WoT, bo, x1, nullptr, x, alpha, NN, DD, DD, 313, 1,
        ln2g, ln2b, xn);

    // FFN up + GELU (1256 blocks, nby=8, XCD-swizzled)
    gemm_bf16<128, 128, 1><<<1256, 256, 0, stream>>>(
        xn, W1T, b1, nullptr, ff1, nullptr, nullptr, NN, DD, FFD, 1256, 8);
    // FFN down + residual (626 blocks, nby=2, XCD-swizzled)
    gemm_bf16<64, 128, 2><<<626, 256, 0, stream>>>(
        ff1, W2T, b2, out, nullptr, x1, beta, NN, FFD, DD, 626, 2);
}

// Round 23
// 245.404 us; speedup vs baseline: 1.0475x; 1.0475x over previous
//
#include <hip/hip_runtime.h>
#include <math.h>

// Problem constants (match reference)
#define NN 20000
#define EE 320000
#define DD 256
#define HH 8
#define DHD 32
#define EDF 64
#define FFD 1024

typedef unsigned short u16;
typedef __attribute__((ext_vector_type(8))) __bf16 bf16x8;
typedef __attribute__((ext_vector_type(8))) unsigned short u16x8;
typedef __attribute__((ext_vector_type(4))) float f32x4;

// workspace float offsets
#define XN_OFF   (0)
#define AGGB_OFF (2560000)
#define X1_OFF   (5120000)    // x1 bf16 [NN][256]
#define QKV_OFF  (10240000)   // q bf16 [NN][256] + kv bf16 [NN][512] (k|v planes)
#define EP_OFF   (25600000)   // epc bf16 [EE][32] CSR-ordered
#define WT_OFF   (35840000)
#define BQKV_OFF (36240000)
#define CSR_OFF  (36250000)

__device__ __forceinline__ u16 f2bf(float f) {
    unsigned u = __float_as_uint(f);
    return (u16)((u + 0x7FFFu + ((u >> 16) & 1u)) >> 16);
}
__device__ __forceinline__ float bf2f(u16 h) {
    return __uint_as_float(((unsigned)h) << 16);
}
__device__ __forceinline__ float gelu_exact(float v) {
    return 0.5f * v * (1.0f + erff(v * 0.70710678118654752f));
}
// XCD-aware bijective swizzle (m204): XCD k gets contiguous work range.
__device__ __forceinline__ int xcd_swz(int bid, int nwg) {
    int q = nwg >> 3, r = nwg & 7;
    int xcd = bid & 7, i = bid >> 3;
    return (xcd < r ? xcd * (q + 1) : r * (q + 1) + (xcd - r) * q) + i;
}

#define GLDS16(g, l) __builtin_amdgcn_global_load_lds(             \
    (__attribute__((address_space(1))) void*)(g),                  \
    (__attribute__((address_space(3))) void*)(l), 16, 0, 0)

// -------- LayerNorm (fp32 in) -> bf16 body --------
__device__ __forceinline__ void ln_body(const float* __restrict__ x,
                                        const float* __restrict__ g,
                                        const float* __restrict__ b,
                                        u16* __restrict__ out, int vb) {
    int row = vb * 4 + (threadIdx.x >> 6);
    if (row >= NN) return;
    int lane = threadIdx.x & 63;
    float4 v = *(const float4*)&x[(size_t)row * DD + lane * 4];
    float s  = v.x + v.y + v.z + v.w;
    float ss = v.x * v.x + v.y * v.y + v.z * v.z + v.w * v.w;
    #pragma unroll
    for (int o = 32; o >= 1; o >>= 1) {
        s  += __shfl_xor(s, o);
        ss += __shfl_xor(ss, o);
    }
    float mean = s * (1.0f / DD);
    float var  = ss * (1.0f / DD) - mean * mean;
    float inv  = rsqrtf(var + 1e-5f);
    float4 gg = *(const float4*)&g[lane * 4];
    float4 bb = *(const float4*)&b[lane * 4];
    ushort4 o4;
    o4.x = f2bf((v.x - mean) * inv * gg.x + bb.x);
    o4.y = f2bf((v.y - mean) * inv * gg.y + bb.y);
    o4.z = f2bf((v.z - mean) * inv * gg.z + bb.z);
    o4.w = f2bf((v.w - mean) * inv * gg.w + bb.w);
    *(ushort4*)&out[(size_t)row * DD + lane * 4] = o4;
}

// -------- LayerNorm (bf16 in) -> bf16: LN2 reads bf16 x1 --------
__global__ __launch_bounds__(256) void ln_b_kernel(const u16* __restrict__ xb,
                                                   const float* __restrict__ g,
                                                   const float* __restrict__ b,
                                                   u16* __restrict__ out) {
    int row = blockIdx.x * 4 + (threadIdx.x >> 6);
    if (row >= NN) return;
    int lane = threadIdx.x & 63;
    ushort4 h = *(const ushort4*)&xb[(size_t)row * DD + lane * 4];
    float4 v = make_float4(bf2f(h.x), bf2f(h.y), bf2f(h.z), bf2f(h.w));
    float s  = v.x + v.y + v.z + v.w;
    float ss = v.x * v.x + v.y * v.y + v.z * v.z + v.w * v.w;
    #pragma unroll
    for (int o = 32; o >= 1; o >>= 1) {
        s  += __shfl_xor(s, o);
        ss += __shfl_xor(ss, o);
    }
    float mean = s * (1.0f / DD);
    float var  = ss * (1.0f / DD) - mean * mean;
    float inv  = rsqrtf(var + 1e-5f);
    float4 gg = *(const float4*)&g[lane * 4];
    float4 bb = *(const float4*)&b[lane * 4];
    ushort4 o4;
    o4.x = f2bf((v.x - mean) * inv * gg.x + bb.x);
    o4.y = f2bf((v.y - mean) * inv * gg.y + bb.y);
    o4.z = f2bf((v.z - mean) * inv * gg.z + bb.z);
    o4.w = f2bf((v.w - mean) * inv * gg.w + bb.w);
    *(ushort4*)&out[(size_t)row * DD + lane * 4] = o4;
}

// -------- 64x64 tile transpose+convert via LDS --------
__device__ __forceinline__ void transp_body(const float* __restrict__ src,
                                            u16* __restrict__ dst,
                                            int K, int N, int k0, int n0) {
    __shared__ float Ws[64][65];
    int t = threadIdx.x;
    int rr = t >> 4, cc = (t & 15) * 4;
    if (n0 + cc < N) {
        #pragma unroll
        for (int p = 0; p < 4; p++) {
            int k = rr + p * 16;
            float4 v = *(const float4*)&src[(size_t)(k0 + k) * N + n0 + cc];
            Ws[k][cc + 0] = v.x; Ws[k][cc + 1] = v.y;
            Ws[k][cc + 2] = v.z; Ws[k][cc + 3] = v.w;
        }
    }
    __syncthreads();
    int n = t >> 2, kc = (t & 3) * 16;
    if (n0 + n < N) {
        u16 o[16];
        #pragma unroll
        for (int j = 0; j < 16; j++) o[j] = f2bf(Ws[kc + j][n]);
        u16* dp = dst + (size_t)(n0 + n) * K + k0 + kc;
        *(ushort4*)(dp + 0)  = *(ushort4*)&o[0];
        *(ushort4*)(dp + 4)  = *(ushort4*)&o[4];
        *(ushort4*)(dp + 8)  = *(ushort4*)&o[8];
        *(ushort4*)(dp + 12) = *(ushort4*)&o[12];
    }
}

// ======== merged: weight transpose + bias + CSR count + LN1 ========
__global__ __launch_bounds__(256) void prep_count_ln_kernel(
    const float* __restrict__ Wq, const float* __restrict__ Wk,
    const float* __restrict__ Wv, const float* __restrict__ Wo,
    const float* __restrict__ W1, const float* __restrict__ W2,
    const float* __restrict__ We,
    const float* __restrict__ bq, const float* __restrict__ bk,
    const float* __restrict__ bv,
    u16* __restrict__ WqkvT, u16* __restrict__ WoT, u16* __restrict__ W1T,
    u16* __restrict__ W2T, u16* __restrict__ WeT, float* __restrict__ bqkv,
    const int* __restrict__ ei, int* __restrict__ counts,
    const float* __restrict__ x, const float* __restrict__ ln1g,
    const float* __restrict__ ln1b, u16* __restrict__ xn) {
    int b = blockIdx.x;
    if (b < 193) {
        const float* src; u16* dst; int K, N, ti;
        if      (b < 16)  { src = Wq; dst = WqkvT;          K = 256;  N = 256;  ti = b; }
        else if (b < 32)  { src = Wk; dst = WqkvT + 65536;  K = 256;  N = 256;  ti = b - 16; }
        else if (b < 48)  { src = Wv; dst = WqkvT + 131072; K = 256;  N = 256;  ti = b - 32; }
        else if (b < 64)  { src = Wo; dst = WoT;            K = 256;  N = 256;  ti = b - 48; }
        else if (b < 128) { src = W1; dst = W1T;            K = 256;  N = 1024; ti = b - 64; }
        else if (b < 192) { src = W2; dst = W2T;            K = 1024; N = 256;  ti = b - 128; }
        else              { src = We; dst = WeT;            K = 64;   N = 32;   ti = 0; }
        int ntn = N >> 6; if (ntn == 0) ntn = 1;
        int tk = ti / ntn, tn = ti % ntn;
        transp_body(src, dst, K, N, tk * 64, tn * 64);
    } else if (b == 193) {
        int t = threadIdx.x;
        bqkv[t] = bq[t];
        bqkv[256 + t] = bk[t];
        bqkv[512 + t] = bv[t];
    } else if (b < 1444) {
        int e = (b - 194) * 256 + threadIdx.x;
        if (e < EE) atomicAdd(&counts[ei[EE + e]], 1);
    } else {
        ln_body(x, ln1g, ln1b, xn, b - 1444);
    }
}

// ======== bf16 MFMA GEMM body ========
// EPI: 0 fp32 out | 1 gelu->bf16 | 2 fp32 res+scale*(acc+bias)
//      3 QKV split (q bf16 scaled, kv k|v planes)
//      5 fp32 out = bf16res + scale*(acc+bias)  (FFN-down, x1 bf16)
//      6 bf16 out = bf16(fp32res + scale*(acc+bias))  (Wo, x1 bf16)
template <int BM, int BN, int EPI>
__device__ __forceinline__ void gemm_body(
    char* smem,
    const u16* __restrict__ A, const u16* __restrict__ BT,
    const float* __restrict__ bias,
    float* __restrict__ Cf, u16* __restrict__ Cb,
    const float* __restrict__ res, const float* __restrict__ scale,
    int M, int K, int N, int bxx, int byy,
    const u16* __restrict__ resb = nullptr)
{
    constexpr int FM = BM / 32, FN = BN / 32;
    constexpr int nA = BM / 32, nB = BN / 32;
    constexpr int NST = (nA > nB) ? nA : nB;
    u16* Asm = (u16*)smem;
    u16* Bsm = (u16*)(smem + BM * 64 * 2);
    const int tid  = threadIdx.x;
    const int lane = tid & 63;
    const int w    = tid >> 6;
    const int wr   = w >> 1, wc = w & 1;
    const int bm   = bxx * BM;
    const int bn   = byy * BN;

    f32x4 acc[FM][FN] = {};

    int st_row[NST], st_src[NST], st_dst[NST];
    #pragma unroll
    for (int i = 0; i < NST; i++) {
        int base  = i * 4096 + w * 1024;
        int off   = base + lane * 16;
        int row   = off >> 7;
        int inner = off & 127;
        st_row[i] = row;
        st_src[i] = (inner ^ ((row & 7) << 4)) >> 1;
        st_dst[i] = base;
    }
    const int arow0 = wr * (BM / 2) + (lane & 15);
    const int brow0 = wc * (BN / 2) + (lane & 15);
    const int kb0   = (lane >> 4) * 16;

    for (int k0 = 0; k0 < K; k0 += 64) {
        #pragma unroll
        for (int i = 0; i < nA; i++) {
            int r = bm + st_row[i]; if (r > M - 1) r = M - 1;
            GLDS16(A + (size_t)r * K + k0 + st_src[i], (char*)Asm + st_dst[i]);
        }
        #pragma unroll
        for (int i = 0; i < nB; i++) {
            int r = bn + st_row[i];
            GLDS16(BT + (size_t)r * K + k0 + st_src[i], (char*)Bsm + st_dst[i]);
        }
        asm volatile("s_waitcnt vmcnt(0)" ::: "memory");
        __syncthreads();
        #pragma unroll
        for (int s = 0; s < 2; s++) {
            bf16x8 af[FM], bfv[FN];
            #pragma unroll
            for (int i = 0; i < FM; i++) {
                int row  = arow0 + i * 16;
                int byte = (row << 7) + ((kb0 + s * 64) ^ ((row & 7) << 4));
                af[i] = *(const bf16x8*)((const char*)Asm + byte);
            }
            #pragma unroll
            for (int j = 0; j < FN; j++) {
                int row  = brow0 + j * 16;
                int byte = (row << 7) + ((kb0 + s * 64) ^ ((row & 7) << 4));
                bfv[j] = *(const bf16x8*)((const char*)Bsm + byte);
            }
            #pragma unroll
            for (int i = 0; i < FM; i++)
                #pragma unroll
                for (int j = 0; j < FN; j++)
                    acc[i][j] = __builtin_amdgcn_mfma_f32_16x16x32_bf16(
                        af[i], bfv[j], acc[i][j], 0, 0, 0);
        }
        __syncthreads();
    }

    float sc = 0.f;
    if constexpr (EPI == 2 || EPI == 5 || EPI == 6) sc = scale[0];
    const int col0 = bn + wc * (BN / 2) + (lane & 15);
    const int row0 = bm + wr * (BM / 2) + ((lane >> 4) << 2);
    #pragma unroll
    for (int i = 0; i < FM; i++) {
        #pragma unroll
        for (int j = 0; j < FN; j++) {
            int col = col0 + j * 16;
            float bb = bias[col];
            #pragma unroll
            for (int r = 0; r < 4; r++) {
                int row = row0 + i * 16 + r;
                if (row < M) {
                    float o = acc[i][j][r] + bb;
                    if constexpr (EPI == 1) {
                        Cb[(size_t)row * N + col] = f2bf(gelu_exact(o));
                    } else if constexpr (EPI == 2) {
                        Cf[(size_t)row * N + col] = res[(size_t)row * N + col] + sc * o;
                    } else if constexpr (EPI == 5) {
                        Cf[(size_t)row * N + col] =
                            bf2f(resb[(size_t)row * N + col]) + sc * o;
                    } else if constexpr (EPI == 6) {
                        Cb[(size_t)row * N + col] =
                            f2bf(res[(size_t)row * N + col] + sc * o);
                    } else if constexpr (EPI == 3) {
                        if (col < 256) {
                            Cb[(size_t)row * 256 + col] = f2bf(o * 0.17677669529663689f);
                        } else if (col < 512) {
                            Cb[(size_t)NN * 256 + (size_t)row * 512 + (col - 256)] = f2bf(o);
                        } else {
                            Cb[(size_t)NN * 256 + (size_t)row * 512 + 256 + (col - 512)] = f2bf(o);
                        }
                    } else {
                        Cf[(size_t)row * N + col] = o;
                    }
                }
            }
        }
    }
}

// 1D-launched GEMM with XCD swizzle (col-tile fastest within an XCD range)
template <int BM, int BN, int EPI>
__global__ __launch_bounds__(256) void gemm_bf16(
    const u16* __restrict__ A, const u16* __restrict__ BT,
    const float* __restrict__ bias,
    float* __restrict__ Cf, u16* __restrict__ Cb,
    const float* __restrict__ res, const float* __restrict__ scale,
    int M, int K, int N, int nwg, int nby,
    const u16* resb = nullptr) {
    __shared__ char smem[(BM + BN) * 64 * 2];
    int wk = xcd_swz(blockIdx.x, nwg);
    gemm_body<BM, BN, EPI>(smem, A, BT, bias, Cf, Cb, res, scale, M, K, N,
                           wk / nby, wk % nby, resb);
}

// -------- edge projection body (128 edges/block) --------
__device__ __forceinline__ void ep_body(char* smem,
                                        const float* __restrict__ ef,
                                        const u16* __restrict__ WeT,
                                        const float* __restrict__ be,
                                        const int* __restrict__ epos,
                                        u16* __restrict__ epc, int blk) {
    const int tid  = threadIdx.x;
    const int lane = tid & 63;
    const int w    = tid >> 6;
    const int e0b  = blk * 128;

    #pragma unroll
    for (int j = 0; j < 8; j++) {
        int gidx = (w * 8 + j) * 64 + lane;
        int e    = gidx >> 4;
        int cs   = (gidx & 15) << 4;
        int c    = cs ^ ((e & 15) << 4);
        GLDS16((const char*)ef + (size_t)(e0b + e) * 256 + c,
               smem + (w * 8 + j) * 1024);
    }
    asm volatile("s_waitcnt vmcnt(0)" ::: "memory");
    __syncthreads();

    const int ar = lane & 15;
    f32x4 acc[2][2] = {};
    #pragma unroll
    for (int t = 0; t < 2; t++) {
        int r = w * 32 + t * 16 + ar;
        const char* base = smem + r * 256;
        #pragma unroll
        for (int s = 0; s < 2; s++) {
            int cbyte = (lane >> 4) * 32 + s * 128;
            float4 a0 = *(const float4*)(base + ((cbyte)      ^ (ar << 4)));
            float4 a1 = *(const float4*)(base + ((cbyte + 16) ^ (ar << 4)));
            bf16x8 af;
            af[0] = (__bf16)a0.x; af[1] = (__bf16)a0.y; af[2] = (__bf16)a0.z; af[3] = (__bf16)a0.w;
            af[4] = (__bf16)a1.x; af[5] = (__bf16)a1.y; af[6] = (__bf16)a1.z; af[7] = (__bf16)a1.w;
            #pragma unroll
            for (int j = 0; j < 2; j++) {
                bf16x8 bf = *(const bf16x8*)&WeT[(size_t)(j * 16 + ar) * EDF + s * 32 + ((lane >> 4) * 8)];
                acc[t][j] = __builtin_amdgcn_mfma_f32_16x16x32_bf16(af, bf, acc[t][j], 0, 0, 0);
            }
        }
    }
    __syncthreads();
    u16* outl = (u16*)smem;
    int* posl = (int*)(smem + 8192);
    if (tid < 128) posl[tid] = epos[e0b + tid];
    const int row0 = (lane >> 4) << 2;
    #pragma unroll
    for (int t = 0; t < 2; t++)
        #pragma unroll
        for (int j = 0; j < 2; j++)
            #pragma unroll
            for (int rr = 0; rr < 4; rr++) {
                int row = w * 32 + t * 16 + row0 + rr;
                int col = j * 16 + ar;
                outl[row * 32 + col] = f2bf(acc[t][j][rr] + be[col]);
            }
    __syncthreads();
    #pragma unroll
    for (int c2 = 0; c2 < 2; c2++) {
        int ch = tid + c2 * 256;
        int row = ch >> 2, part = ch & 3;
        u16x8 v = *(const u16x8*)&outl[row * 32 + part * 8];
        *(u16x8*)&epc[(size_t)posl[row] * DHD + part * 8] = v;
    }
}

// ======== merged: QKV GEMM (942, XCD-swizzled) + edge projection (2500) ========
__global__ __launch_bounds__(256) void qkv_ep_kernel(
    const u16* __restrict__ xn, const u16* __restrict__ WqkvT,
    const float* __restrict__ bqkv, u16* __restrict__ qb,
    const float* __restrict__ ef, const u16* __restrict__ WeT,
    const float* __restrict__ be, const int* __restrict__ epos,
    u16* __restrict__ epc) {
    __shared__ char smem[32768];
    int b = blockIdx.x;
    if (b < 942) {
        int wk = xcd_swz(b, 942);
        gemm_body<128, 128, 3>(smem, xn, WqkvT, bqkv, nullptr, qb, nullptr,
                               nullptr, NN, DD, 768, wk / 6, wk % 6);
    } else {
        ep_body(smem, ef, WeT, be, epos, epc, b - 942);
    }
}

// ======== CSR scan + degree histogram ========
__global__ __launch_bounds__(1024) void scan_kernel(const int* __restrict__ counts,
                                                    int* __restrict__ row_start,
                                                    int* __restrict__ cursor,
                                                    int* __restrict__ dcursor) {
    __shared__ int part[1024];
    __shared__ int hist[64][16];
    const int CH = 20;
    int t = threadIdx.x;
    if (t < 64) {
        #pragma unroll
        for (int s = 0; s < 16; s++) hist[t][s] = 0;
    }
    __syncthreads();
    int base = t * CH;
    int sub = t & 15;
    int loc[CH];
    int s = 0;
    #pragma unroll
    for (int i = 0; i < CH; i++) {
        int idx = base + i;
        int c = (idx < NN) ? counts[idx] : 0;
        if (idx < NN) atomicAdd(&hist[min(c, 63)][sub], 1);
        loc[i] = s;
        s += c;
    }
    part[t] = s;
    __syncthreads();
    for (int o = 1; o < 1024; o <<= 1) {
        int vv = (t >= o) ? part[t - o] : 0;
        __syncthreads();
        part[t] += vv;
        __syncthreads();
    }
    int off = (t > 0) ? part[t - 1] : 0;
    #pragma unroll
    for (int i = 0; i < CH; i++) {
        int idx = base + i;
        if (idx < NN) {
            int rs = off + loc[i];
            row_start[idx] = rs;
            cursor[idx] = rs;
        }
    }
    if (t == 1023) row_start[NN] = part[1023];
    if (t < 64) {
        int st = 0;
        for (int b = 63; b > t; --b) {
            #pragma unroll
            for (int sj = 0; sj < 16; sj++) st += hist[b][sj];
        }
        dcursor[t] = st;
    }
}

// fill CSR + epos + block-aggregated counting sort
__global__ __launch_bounds__(256) void fill_kernel(const int* __restrict__ ei,
                                                   const float* __restrict__ ew,
                                                   int* __restrict__ cursor,
                                                   int2* __restrict__ csr,
                                                   int* __restrict__ epos,
                                                   const int* __restrict__ counts,
                                                   int* __restrict__ dcursor,
                                                   int* __restrict__ order) {
    int b = blockIdx.x;
    if (b < EE / 256) {
        int e = b * 256 + threadIdx.x;
        int src = ei[e];
        int dst = ei[EE + e];
        int pos = atomicAdd(&cursor[dst], 1);
        csr[pos] = make_int2(src, __float_as_int(ew[e] * 1.44269504088896f));
        epos[e] = pos;
    } else {
        __shared__ int lhist[64];
        __shared__ int lbase[64];
        int t = threadIdx.x;
        if (t < 64) lhist[t] = 0;
        __syncthreads();
        int n = (b - EE / 256) * 256 + t;
        int d = -1, lpos = 0;
        if (n < NN) {
            d = min(counts[n], 63);
            lpos = atomicAdd(&lhist[d], 1);
        }
        __syncthreads();
        if (t < 64 && lhist[t] > 0) lbase[t] = atomicAdd(&dcursor[t], lhist[t]);
        __syncthreads();
        if (n < NN) order[lbase[d] + lpos] = n;
    }
}

// ======== fused gather attention: ONE WAVE per dst node, degree-sorted ========
__global__ __launch_bounds__(256) void attn_kernel(const u16* __restrict__ qb,
                                                   const u16* __restrict__ kv,
                                                   const u16* __restrict__ epc,
                                                   const int2* __restrict__ csr,
                                                   const int* __restrict__ row_start,
                                                   const int* __restrict__ order,
                                                   u16* __restrict__ aggb) {
    const int dst  = order[blockIdx.x * 4 + (threadIdx.x >> 6)];
    const int lane = threadIdx.x & 63;
    const int g    = lane & 7;
    const int d0   = (lane >> 3) * 32 + g * 4;
    const int beg = row_start[dst];
    const int end = row_start[dst + 1];
    ushort4 q4 = *(const ushort4*)&qb[(size_t)dst * DD + d0];
    float4 qv = make_float4(bf2f(q4.x), bf2f(q4.y), bf2f(q4.z), bf2f(q4.w));
    float ss = 0.f;
    float4 acc = make_float4(0.f, 0.f, 0.f, 0.f);

    int i = beg;
    if ((i & 1) && i < end) {
        int2 p = csr[i];
        ushort4 ka = *(const ushort4*)&kv[(size_t)p.x * 512 + d0];
        ushort4 va = *(const ushort4*)&kv[(size_t)p.x * 512 + 256 + d0];
        ushort4 e4 = *(const ushort4*)&epc[(size_t)i * DHD + g * 4];
        float k0 = bf2f(ka.x) + bf2f(e4.x);
        float k1 = bf2f(ka.y) + bf2f(e4.y);
        float k2 = bf2f(ka.z) + bf2f(e4.z);
        float k3 = bf2f(ka.w) + bf2f(e4.w);
        float pv = fmaf(qv.x, k0, fmaf(qv.y, k1, fmaf(qv.z, k2, qv.w * k3)));
        #pragma unroll
        for (int o = 4; o >= 1; o >>= 1) pv += __shfl_xor(pv, o);
        float wq = exp2f(pv * __int_as_float(p.y));
        ss += wq;
        acc.x = fmaf(wq, bf2f(va.x), acc.x);
        acc.y = fmaf(wq, bf2f(va.y), acc.y);
        acc.z = fmaf(wq, bf2f(va.z), acc.z);
        acc.w = fmaf(wq, bf2f(va.w), acc.w);
        ++i;
    }
    for (; i + 4 <= end; i += 4) {
        int4 c01 = *(const int4*)&csr[i];
        int4 c23 = *(const int4*)&csr[i + 2];
        int   sr[4] = {c01.x, c01.z, c23.x, c23.z};
        float wt[4] = {__int_as_float(c01.y), __int_as_float(c01.w),
                       __int_as_float(c23.y), __int_as_float(c23.w)};
        ushort4 ka[4], va[4], e4[4];
        #pragma unroll
        for (int u = 0; u < 4; u++) {
            ka[u] = *(const ushort4*)&kv[(size_t)sr[u] * 512 + d0];
            va[u] = *(const ushort4*)&kv[(size_t)sr[u] * 512 + 256 + d0];
            e4[u] = *(const ushort4*)&epc[(size_t)(i + u) * DHD + g * 4];
        }
        float pp[4];
        #pragma unroll
        for (int u = 0; u < 4; u++) {
            float k0 = bf2f(ka[u].x) + bf2f(e4[u].x);
            float k1 = bf2f(ka[u].y) + bf2f(e4[u].y);
            float k2 = bf2f(ka[u].z) + bf2f(e4[u].z);
            float k3 = bf2f(ka[u].w) + bf2f(e4[u].w);
            pp[u] = fmaf(qv.x, k0, fmaf(qv.y, k1, fmaf(qv.z, k2, qv.w * k3)));
        }
        #pragma unroll
        for (int o = 4; o >= 1; o >>= 1) {
            #pragma unroll
            for (int u = 0; u < 4; u++) pp[u] += __shfl_xor(pp[u], o);
        }
        #pragma unroll
        for (int u = 0; u < 4; u++) {
            float wq = exp2f(pp[u] * wt[u]);
            ss += wq;
            acc.x = fmaf(wq, bf2f(va[u].x), acc.x);
            acc.y = fmaf(wq, bf2f(va[u].y), acc.y);
            acc.z = fmaf(wq, bf2f(va[u].z), acc.z);
            acc.w = fmaf(wq, bf2f(va[u].w), acc.w);
        }
    }
    for (; i < end; ++i) {
        int2 p = csr[i];
        ushort4 ka = *(const ushort4*)&kv[(size_t)p.x * 512 + d0];
        ushort4 va = *(const ushort4*)&kv[(size_t)p.x * 512 + 256 + d0];
        ushort4 e4 = *(const ushort4*)&epc[(size_t)i * DHD + g * 4];
        float k0 = bf2f(ka.x) + bf2f(e4.x);
        float k1 = bf2f(ka.y) + bf2f(e4.y);
        float k2 = bf2f(ka.z) + bf2f(e4.z);
        float k3 = bf2f(ka.w) + bf2f(e4.w);
        float pv = fmaf(qv.x, k0, fmaf(qv.y, k1, fmaf(qv.z, k2, qv.w * k3)));
        #pragma unroll
        for (int o = 4; o >= 1; o >>= 1) pv += __shfl_xor(pv, o);
        float wq = exp2f(pv * __int_as_float(p.y));
        ss += wq;
        acc.x = fmaf(wq, bf2f(va.x), acc.x);
        acc.y = fmaf(wq, bf2f(va.y), acc.y);
        acc.z = fmaf(wq, bf2f(va.z), acc.z);
        acc.w = fmaf(wq, bf2f(va.w), acc.w);
    }
    float inv = (end > beg) ? 1.f / ss : 0.f;
    ushort4 o4;
    o4.x = f2bf(acc.x * inv);
    o4.y = f2bf(acc.y * inv);
    o4.z = f2bf(acc.z * inv);
    o4.w = f2bf(acc.w * inv);
    *(ushort4*)&aggb[(size_t)dst * DD + d0] = o4;
}

extern "C" void kernel_launch(void* const* d_in, const int* in_sizes, int n_in,
                              void* d_out, int out_size, void* d_ws, size_t ws_size,
                              hipStream_t stream) {
    const float* x    = (const float*)d_in[0];
    const float* ef   = (const float*)d_in[1];
    const float* ew   = (const float*)d_in[2];
    const int*   ei   = (const int*)d_in[3];
    const float* Wq   = (const float*)d_in[4];
    const float* bq   = (const float*)d_in[5];
    const float* Wk   = (const float*)d_in[6];
    const float* bk   = (const float*)d_in[7];
    const float* Wv   = (const float*)d_in[8];
    const float* bv   = (const float*)d_in[9];
    const float* We   = (const float*)d_in[10];
    const float* be   = (const float*)d_in[11];
    const float* Wo   = (const float*)d_in[12];
    const float* bo   = (const float*)d_in[13];
    const float* ln1g = (const float*)d_in[14];
    const float* ln1b = (const float*)d_in[15];
    const float* ln2g = (const float*)d_in[16];
    const float* ln2b = (const float*)d_in[17];
    const float* W1   = (const float*)d_in[18];
    const float* b1   = (const float*)d_in[19];
    const float* W2   = (const float*)d_in[20];
    const float* b2   = (const float*)d_in[21];
    const float* alpha = (const float*)d_in[22];
    const float* beta  = (const float*)d_in[23];

    float* ws    = (float*)d_ws;
    u16*   xn    = (u16*)(ws + XN_OFF);
    u16*   aggb  = (u16*)(ws + AGGB_OFF);
    u16*   x1b   = (u16*)(ws + X1_OFF);          // x1 bf16 [NN][256]
    u16*   qb    = (u16*)(ws + QKV_OFF);
    u16*   kv    = qb + (size_t)NN * 256;
    u16*   ff1   = (u16*)(ws + QKV_OFF);
    u16*   epc   = (u16*)(ws + EP_OFF);
    u16*   wt    = (u16*)(ws + WT_OFF);
    u16*   WqkvT = wt;
    u16*   WoT   = wt + 768 * 256;
    u16*   W1T   = WoT + 256 * 256;
    u16*   W2T   = W1T + 1024 * 256;
    u16*   WeT   = W2T + 256 * 1024;
    float* bqkv  = ws + BQKV_OFF;
    float* out   = (float*)d_out;

    int*  counts    = (int*)(ws + CSR_OFF);
    int*  row_start = counts + NN;
    int*  cursor    = row_start + NN + 1;
    int2* csr       = (int2*)(counts + 60004);
    int*  epos      = counts + 60004 + 2 * EE;
    int*  order     = epos + EE;
    int*  dcursor   = order + NN;

    hipMemsetAsync(counts, 0, (size_t)NN * sizeof(int), stream);

    prep_count_ln_kernel<<<6444, 256, 0, stream>>>(
        Wq, Wk, Wv, Wo, W1, W2, We, bq, bk, bv,
        WqkvT, WoT, W1T, W2T, WeT, bqkv, ei, counts, x, ln1g, ln1b, xn);

    scan_kernel<<<1, 1024, 0, stream>>>(counts, row_start, cursor, dcursor);
    fill_kernel<<<EE / 256 + (NN + 255) / 256, 256, 0, stream>>>(
        ei, ew, cursor, csr, epos, counts, dcursor, order);

    // merged QKV GEMM (942, XCD-swizzled) + edge projection (2500)
    qkv_ep_kernel<<<3442, 256, 0, stream>>>(xn, WqkvT, bqkv, qb,
                                            ef, WeT, be, epos, epc);

    attn_kernel<<<NN / 4, 256, 0, stream>>>(qb, kv, epc, csr, row_start, order, aggb);

    // Wo GEMM + residual -> x1 bf16 (626 blocks, nby=2, XCD-swizzled)
    gemm_bf16<64, 128, 6><<<626, 256, 0, stream>>>(
        aggb, WoT, bo, nullptr, x1b, x, alpha, NN, DD, DD, 626, 2);

    // LN2 on bf16 x1
    ln_b_kernel<<<NN / 4, 256, 0, stream>>>(x1b, ln2g, ln2b, xn);

    // FFN up + GELU (1256 blocks, nby=8, XCD-swizzled)
    gemm_bf16<128, 128, 1><<<1256, 256, 0, stream>>>(
        xn, W1T, b1, nullptr, ff1, nullptr, nullptr, NN, DD, FFD, 1256, 8);
    // FFN down + bf16 residual -> out fp32 (626 blocks, nby=2, XCD-swizzled)
    gemm_bf16<64, 128, 5><<<626, 256, 0, stream>>>(
        ff1, W2T, b2, out, nullptr, nullptr, beta, NN, FFD, DD, 626, 2, x1b);
}